// Round 12
// baseline (690.093 us; speedup 1.0000x reference)
//
#include <hip/hip_runtime.h>
#include <hip/hip_bf16.h>

typedef short short8 __attribute__((ext_vector_type(8)));
typedef unsigned short ushort8 __attribute__((ext_vector_type(8)));
typedef unsigned short ushort4v __attribute__((ext_vector_type(4)));
typedef float f32x4 __attribute__((ext_vector_type(4)));
typedef unsigned short ushort;

constexpr float SCALE = 0.125f;   // 64^-0.5
constexpr float EPS_RMS = 1e-6f;

#define BAR() asm volatile("s_barrier" ::: "memory")
#define WAITV(N) asm volatile("s_waitcnt vmcnt(" #N ")" ::: "memory")

__device__ __forceinline__ ushort f2bf(float f) {
  return __builtin_bit_cast(unsigned short, __float2bfloat16(f));
}
__device__ __forceinline__ float bf2f(ushort u) {
  return __bfloat162float(__builtin_bit_cast(__hip_bfloat16, u));
}
__device__ __forceinline__ void gl_lds16(const void* g, void* l) {
  __builtin_amdgcn_global_load_lds((const __attribute__((address_space(1))) void*)g,
                                   (__attribute__((address_space(3))) void*)l, 16, 0, 0);
}

// permuted row p -> natural token row
__device__ __forceinline__ int nat_row(int p) {
  return (p & ~4095) | (((p >> 9) & 7) << 9) | (((p >> 3) & 7) << 6) |
         (((p >> 6) & 7) << 3) | (p & 7);
}

// ============ P0: transpose + split weights into bf16 hi/lo planes ============
__global__ void k_prep(const float* __restrict__ src, int src_ld, int mode,
                       ushort* __restrict__ hi, ushort* __restrict__ lo) {
  __shared__ float tile[64][65];
  int rb = blockIdx.x, db = blockIdx.y;
  int tid = threadIdx.x;
#pragma unroll
  for (int e = 0; e < 16; ++e) {
    int idx = e * 256 + tid;
    int dd = idx >> 6, cc = idx & 63;
    int sc;
    if (mode == 0) { int h = rb / 3, p = rb % 3; sc = p * 768 + h * 64 + cc; }
    else sc = rb * 64 + cc;
    tile[dd][cc] = src[(db * 64 + dd) * src_ld + sc];
  }
  __syncthreads();
#pragma unroll
  for (int e = 0; e < 16; ++e) {
    int idx = e * 256 + tid;
    int cc = idx >> 6, dd = idx & 63;
    float f = tile[dd][cc];
    ushort h = f2bf(f);
    ushort l = f2bf(f - bf2f(h));
    int o = (rb * 64 + cc) * 768 + db * 64 + dd;
    hi[o] = h;
    lo[o] = l;
  }
}

// ============ X: split x into bf16 hi/lo planes, window-permuted rows ============
__global__ void k_xsplit(const float* __restrict__ x,
                         ushort* __restrict__ xh, ushort* __restrict__ xl) {
  int idx = blockIdx.x * 256 + threadIdx.x;   // 32768*96
  int p = idx / 96, seg = idx - p * 96;
  int n = nat_row(p);
  const float* src = x + n * 768 + seg * 8;
  float4 a = *(const float4*)src;
  float4 c = *(const float4*)(src + 4);
  float v[8] = {a.x, a.y, a.z, a.w, c.x, c.y, c.z, c.w};
  ushort8 hi, lo;
#pragma unroll
  for (int j = 0; j < 8; ++j) {
    ushort h = f2bf(v[j]);
    hi[j] = h;
    lo[j] = f2bf(v[j] - bf2f(h));
  }
  *(ushort8*)&xh[p * 768 + seg * 8] = hi;
  *(ushort8*)&xl[p * 768 + seg * 8] = lo;
}

// ============ G1: QKV of the 4 global tokens (4 x 2304), fp32 ============
__global__ void k_gqkv(const float* __restrict__ gtok,
                       const float* __restrict__ w_qkv,
                       float* __restrict__ qkv_g) {
  int idx = blockIdx.x * 256 + threadIdx.x;   // 0..9215
  int tok = idx / 2304, c = idx - tok * 2304;
  const float* gp = gtok + tok * 768;
  float s = 0.f;
  for (int d = 0; d < 768; ++d) s += gp[d] * w_qkv[d * 2304 + c];
  qkv_g[idx] = s;
}

// attention LDS layout (float offsets, stride 68 = 17 float4 units)
#define QS_OFF 0        // q rows [64][68]   (aliased as P after softmax)
#define KT_OFF 4352     // k^T    [64(d)][68(tok)]  (RAW k, transposed)
#define VS_OFF 8704     // v rows [64][68]
#define SQ_OFF 13056    // sq[64]
#define SK_OFF 13120    // sk[64]
#define PC_OFF 13248    // ps_c[256]

// ============ F: fused QKV-GEMM (128x192, 4-plane BK=32) + attention ============
// 256 threads (4 waves), 80KB LDS -> 2 blocks/CU. At (256,2) the per-wave VGPR
// cap is 256 (2 waves/SIMD), so the 4-row attention tile fits without spill.
__global__ __launch_bounds__(256, 2) void k_fused(
    const ushort* __restrict__ xh, const ushort* __restrict__ xl,
    const ushort* __restrict__ Whi, const ushort* __restrict__ Wlo,
    const float* __restrict__ qnw, const float* __restrict__ knw,
    const float* __restrict__ qkv_g, float* __restrict__ part,
    ushort* __restrict__ o_hi, ushort* __restrict__ o_lo) {
  __shared__ __align__(16) char smem[81920];   // GEMM: 2 x 40KB ; attn: 54KB
  const int tid = threadIdx.x;
  const int lane = tid & 63;
  const int wv = tid >> 6;                     // 0..3
  const int wm = wv >> 1, wn = wv & 1;         // 2M x 2N, wave tile 64x96
  const int l15 = lane & 15, kq = lane >> 4;
  const int bid = blockIdx.x;
  const int xcd = bid & 7, kk_ = bid >> 3;
  const int h = kk_ % 12;
  const int mblk = (kk_ / 12) * 8 + xcd;       // 0..255
  const int r0 = mblk * 128;
  const int cb0 = h * 192;

  // staging maps: A region 16KB (Ah|Al), B region 24KB (Bh|Bl), 16B/thread-load
  int gAo[4], lA[4]; bool pA[4];
#pragma unroll
  for (int j = 0; j < 4; ++j) {
    int byo = (j * 256 + tid) * 16;            // 0..16383
    pA[j] = byo >= 8192;
    int wb = byo & 8191;
    int row = wb >> 6, sl = (wb >> 4) & 3;
    int kb = sl ^ ((row >> 1) & 3);
    gAo[j] = (r0 + row) * 768 + kb * 8;
    lA[j] = byo;
  }
  int gBo[6], lB[6]; bool pB[6];
#pragma unroll
  for (int j = 0; j < 6; ++j) {
    int byo = (j * 256 + tid) * 16;            // 0..24575
    pB[j] = byo >= 12288;
    int wb = pB[j] ? byo - 12288 : byo;
    int row = wb >> 6, sl = (wb >> 4) & 3;
    int kb = sl ^ ((row >> 1) & 3);
    gBo[j] = (cb0 + row) * 768 + kb * 8;
    lB[j] = 16384 + byo;
  }

  f32x4 acc[4][6];
#pragma unroll
  for (int i = 0; i < 4; ++i)
#pragma unroll
    for (int j = 0; j < 6; ++j) acc[i][j] = (f32x4){0.f, 0.f, 0.f, 0.f};

  auto STAGE = [&](int t, int bufi) {
    const int kk = t * 32;
    char* bb = smem + bufi * 40960;
#pragma unroll
    for (int j = 0; j < 4; ++j) {
      const ushort* Ap = pA[j] ? xl : xh;
      gl_lds16(Ap + gAo[j] + kk, bb + lA[j]);
    }
#pragma unroll
    for (int j = 0; j < 6; ++j) {
      const ushort* Bp = pB[j] ? Wlo : Whi;
      gl_lds16(Bp + gBo[j] + kk, bb + lB[j]);
    }
  };

  auto COMPUTE = [&](int bufi) {
    const char* ba = smem + bufi * 40960;
    short8 ah[4], al[4], bh[6], bl[6];
#pragma unroll
    for (int mf = 0; mf < 4; ++mf) {
      int row = wm * 64 + mf * 16 + l15;
      int so = (kq ^ ((row >> 1) & 3)) << 4;
      ah[mf] = *(const short8*)(ba + row * 64 + so);
      al[mf] = *(const short8*)(ba + 8192 + row * 64 + so);
    }
#pragma unroll
    for (int nf = 0; nf < 6; ++nf) {
      int row = wn * 96 + nf * 16 + l15;
      int so = (kq ^ ((row >> 1) & 3)) << 4;
      bh[nf] = *(const short8*)(ba + 16384 + row * 64 + so);
      bl[nf] = *(const short8*)(ba + 28672 + row * 64 + so);
    }
#pragma unroll
    for (int mf = 0; mf < 4; ++mf)
#pragma unroll
      for (int nf = 0; nf < 6; ++nf) {
        acc[mf][nf] = __builtin_amdgcn_mfma_f32_16x16x32_bf16(ah[mf], bh[nf], acc[mf][nf], 0, 0, 0);
        acc[mf][nf] = __builtin_amdgcn_mfma_f32_16x16x32_bf16(ah[mf], bl[nf], acc[mf][nf], 0, 0, 0);
        acc[mf][nf] = __builtin_amdgcn_mfma_f32_16x16x32_bf16(al[mf], bh[nf], acc[mf][nf], 0, 0, 0);
      }
  };

  STAGE(0, 0); STAGE(1, 1);
  WAITV(10); BAR();
  for (int t = 0; t < 24; ++t) {
    int cur = t & 1;
    COMPUTE(cur);
    BAR();
    if (t < 22) { STAGE(t + 2, cur); WAITV(10); }
    else { WAITV(0); }
    BAR();
  }

  // ======== attention: 2 passes x 1 window; 4-row register tiles ========
  const int tl = tid;
  float* gb = (float*)smem;
  for (int pass = 0; pass < 2; ++pass) {
    // scatter this pass's window (waves with wm==pass): q rows, k^T (raw), v rows
    if (wm == pass) {
#pragma unroll
      for (int mf = 0; mf < 4; ++mf) {
#pragma unroll
        for (int nf = 0; nf < 6; ++nf) {
          int col = wn * 96 + nf * 16 + l15;
#pragma unroll
          for (int e = 0; e < 4; ++e) {
            int tok = mf * 16 + kq * 4 + e;
            float val = acc[mf][nf][e];
            if (col < 64)       gb[QS_OFF + tok * 68 + col] = val;
            else if (col < 128) gb[KT_OFF + (col - 64) * 68 + tok] = val;
            else                gb[VS_OFF + tok * 68 + (col - 128)] = val;
          }
        }
      }
    }
    __syncthreads();

    const int widx = mblk * 2 + pass;
    const int b = widx >> 6, wl = widx & 63;

    // ---- phase C: global-attn partials (raw k^T, raw v) ----
    {
      int qi = tl >> 6, j = tl & 63;
      const float* qgp = qkv_g + qi * 2304 + h * 64;
      float s = 0.f;
#pragma unroll 16
      for (int d = 0; d < 64; ++d) s += qgp[d] * gb[KT_OFF + d * 68 + j];
      s *= SCALE;
      float m = s;
#pragma unroll
      for (int o = 1; o < 64; o <<= 1) m = fmaxf(m, __shfl_xor(m, o));
      float p = expf(s - m);
      float l = p;
#pragma unroll
      for (int o = 1; o < 64; o <<= 1) l += __shfl_xor(l, o);
      gb[PC_OFF + qi * 64 + j] = p;
      int pbase = ((b * 12 + h) * 64 + wl) * 272;
      if (j == 0) { part[pbase + 256 + qi] = m; part[pbase + 260 + qi] = l; }
      __syncthreads();
      float a = 0.f;
#pragma unroll 16
      for (int jj = 0; jj < 64; ++jj) a += gb[PC_OFF + qi * 64 + jj] * gb[VS_OFF + jj * 68 + j];
      part[pbase + qi * 64 + j] = a;
    }
    __syncthreads();

    // ---- rms scales: sq from q rows (f32x4), sk from kT cols ----
    if (tl < 64) {
      float ss = 0.f;
#pragma unroll
      for (int d4 = 0; d4 < 16; ++d4) {
        f32x4 v = *(const f32x4*)&gb[QS_OFF + tl * 68 + d4 * 4];
        ss += v[0] * v[0] + v[1] * v[1] + v[2] * v[2] + v[3] * v[3];
      }
      gb[SQ_OFF + tl] = 1.0f / sqrtf(ss * 0.015625f + EPS_RMS);
    } else if (tl < 128) {
      int c = tl - 64;
      float ss = 0.f;
#pragma unroll 16
      for (int d = 0; d < 64; ++d) { float t = gb[KT_OFF + d * 68 + c]; ss += t * t; }
      gb[SK_OFF + c] = 1.0f / sqrtf(ss * 0.015625f + EPS_RMS);
    }
    __syncthreads();

    // ---- phase B: local attention, 4-row tiles (k/v read once per 4 rows) ----
    {
      const int ty = tl >> 4, tx = tl & 15;
      const int r0q = ty * 4, c0k = tx * 4;
      const f32x4* qnw4 = (const f32x4*)qnw;
      const f32x4* knw4 = (const f32x4*)knw;
      const f32x4 skv = *(const f32x4*)&gb[SK_OFF + c0k];
      f32x4 X[4];
      X[0] = X[1] = X[2] = X[3] = (f32x4){0.f, 0.f, 0.f, 0.f};
#pragma unroll
      for (int d4 = 0; d4 < 16; ++d4) {
        f32x4 ww = qnw4[d4] * knw4[d4];
        f32x4 k0 = *(const f32x4*)&gb[KT_OFF + (d4 * 4 + 0) * 68 + c0k];
        f32x4 k1 = *(const f32x4*)&gb[KT_OFF + (d4 * 4 + 1) * 68 + c0k];
        f32x4 k2 = *(const f32x4*)&gb[KT_OFF + (d4 * 4 + 2) * 68 + c0k];
        f32x4 k3 = *(const f32x4*)&gb[KT_OFF + (d4 * 4 + 3) * 68 + c0k];
#pragma unroll
        for (int r = 0; r < 4; ++r) {
          f32x4 qv = *(const f32x4*)&gb[QS_OFF + (r0q + r) * 68 + d4 * 4];
          qv *= ww;
          X[r] += qv[0] * k0 + qv[1] * k1 + qv[2] * k2 + qv[3] * k3;
        }
      }
      float li[4];
#pragma unroll
      for (int r = 0; r < 4; ++r) {
        X[r] = X[r] * skv * (gb[SQ_OFF + r0q + r] * SCALE);
        float m = fmaxf(fmaxf(X[r][0], X[r][1]), fmaxf(X[r][2], X[r][3]));
#pragma unroll
        for (int o = 1; o < 16; o <<= 1) m = fmaxf(m, __shfl_xor(m, o));
#pragma unroll
        for (int cc = 0; cc < 4; ++cc) X[r][cc] = expf(X[r][cc] - m);
        float s = X[r][0] + X[r][1] + X[r][2] + X[r][3];
#pragma unroll
        for (int o = 1; o < 16; o <<= 1) s += __shfl_xor(s, o);
        li[r] = 1.0f / s;
      }
      __syncthreads();     // all q reads done before P overwrites q region
#pragma unroll
      for (int r = 0; r < 4; ++r)
        *(f32x4*)&gb[QS_OFF + (r0q + r) * 68 + c0k] = X[r];
      __syncthreads();
      f32x4 O[4];
      O[0] = O[1] = O[2] = O[3] = (f32x4){0.f, 0.f, 0.f, 0.f};
#pragma unroll
      for (int j4 = 0; j4 < 16; ++j4) {
        f32x4 v0 = *(const f32x4*)&gb[VS_OFF + (j4 * 4 + 0) * 68 + c0k];
        f32x4 v1 = *(const f32x4*)&gb[VS_OFF + (j4 * 4 + 1) * 68 + c0k];
        f32x4 v2 = *(const f32x4*)&gb[VS_OFF + (j4 * 4 + 2) * 68 + c0k];
        f32x4 v3 = *(const f32x4*)&gb[VS_OFF + (j4 * 4 + 3) * 68 + c0k];
#pragma unroll
        for (int r = 0; r < 4; ++r) {
          f32x4 pv = *(const f32x4*)&gb[QS_OFF + (r0q + r) * 68 + j4 * 4];
          O[r] += pv[0] * v0 + pv[1] * v1 + pv[2] * v2 + pv[3] * v3;
        }
      }
#pragma unroll
      for (int r = 0; r < 4; ++r) {
        O[r] *= li[r];
        int orow = (widx * 64 + r0q + r) * 768 + h * 64 + c0k;
        ushort4v hv, lv;
#pragma unroll
        for (int cc = 0; cc < 4; ++cc) {
          float a = O[r][cc];
          ushort hh = f2bf(a);
          hv[cc] = hh;
          lv[cc] = f2bf(a - bf2f(hh));
        }
        *(ushort4v*)&o_hi[orow] = hv;
        *(ushort4v*)&o_lo[orow] = lv;
      }
    }
    __syncthreads();
  }
}

// ============ P: projection out = o @ w_out + g_term (128x192, 4-plane BK=32) ====
// 256 threads, 80KB LDS -> 2 blocks/CU. grid = 1024, XCD-local decode.
__global__ __launch_bounds__(256, 2) void k_proj8(
    const ushort* __restrict__ o_hi, const ushort* __restrict__ o_lo,
    const ushort* __restrict__ Whi, const ushort* __restrict__ Wlo,
    const float* __restrict__ g_term, float* __restrict__ out) {
  __shared__ __align__(16) char smem[81920];
  const int tid = threadIdx.x;
  const int lane = tid & 63;
  const int wv = tid >> 6;
  const int wm = wv >> 1, wn = wv & 1;
  const int l15 = lane & 15, kq = lane >> 4;
  const int bid = blockIdx.x;
  const int xcd = bid & 7, kk_ = bid >> 3;     // 0..127
  const int cblk = kk_ % 4;
  const int mblk = (kk_ / 4) * 8 + xcd;        // 0..255
  const int r0 = mblk * 128;
  const int cb0 = cblk * 192;

  int gAo[4], lA[4]; bool pA[4];
#pragma unroll
  for (int j = 0; j < 4; ++j) {
    int byo = (j * 256 + tid) * 16;
    pA[j] = byo >= 8192;
    int wb = byo & 8191;
    int row = wb >> 6, sl = (wb >> 4) & 3;
    int kb = sl ^ ((row >> 1) & 3);
    gAo[j] = (r0 + row) * 768 + kb * 8;
    lA[j] = byo;
  }
  int gBo[6], lB[6]; bool pB[6];
#pragma unroll
  for (int j = 0; j < 6; ++j) {
    int byo = (j * 256 + tid) * 16;
    pB[j] = byo >= 12288;
    int wb = pB[j] ? byo - 12288 : byo;
    int row = wb >> 6, sl = (wb >> 4) & 3;
    int kb = sl ^ ((row >> 1) & 3);
    gBo[j] = (cb0 + row) * 768 + kb * 8;
    lB[j] = 16384 + byo;
  }

  f32x4 acc[4][6];
#pragma unroll
  for (int i = 0; i < 4; ++i)
#pragma unroll
    for (int j = 0; j < 6; ++j) acc[i][j] = (f32x4){0.f, 0.f, 0.f, 0.f};

  auto STAGE = [&](int t, int bufi) {
    const int kk = t * 32;
    char* bb = smem + bufi * 40960;
#pragma unroll
    for (int j = 0; j < 4; ++j) {
      const ushort* Ap = pA[j] ? o_lo : o_hi;
      gl_lds16(Ap + gAo[j] + kk, bb + lA[j]);
    }
#pragma unroll
    for (int j = 0; j < 6; ++j) {
      const ushort* Bp = pB[j] ? Wlo : Whi;
      gl_lds16(Bp + gBo[j] + kk, bb + lB[j]);
    }
  };

  auto COMPUTE = [&](int bufi) {
    const char* ba = smem + bufi * 40960;
    short8 ah[4], al[4], bh[6], bl[6];
#pragma unroll
    for (int mf = 0; mf < 4; ++mf) {
      int row = wm * 64 + mf * 16 + l15;
      int so = (kq ^ ((row >> 1) & 3)) << 4;
      ah[mf] = *(const short8*)(ba + row * 64 + so);
      al[mf] = *(const short8*)(ba + 8192 + row * 64 + so);
    }
#pragma unroll
    for (int nf = 0; nf < 6; ++nf) {
      int row = wn * 96 + nf * 16 + l15;
      int so = (kq ^ ((row >> 1) & 3)) << 4;
      bh[nf] = *(const short8*)(ba + 16384 + row * 64 + so);
      bl[nf] = *(const short8*)(ba + 28672 + row * 64 + so);
    }
#pragma unroll
    for (int mf = 0; mf < 4; ++mf)
#pragma unroll
      for (int nf = 0; nf < 6; ++nf) {
        acc[mf][nf] = __builtin_amdgcn_mfma_f32_16x16x32_bf16(ah[mf], bh[nf], acc[mf][nf], 0, 0, 0);
        acc[mf][nf] = __builtin_amdgcn_mfma_f32_16x16x32_bf16(ah[mf], bl[nf], acc[mf][nf], 0, 0, 0);
        acc[mf][nf] = __builtin_amdgcn_mfma_f32_16x16x32_bf16(al[mf], bh[nf], acc[mf][nf], 0, 0, 0);
      }
  };

  STAGE(0, 0); STAGE(1, 1);
  WAITV(10); BAR();
  for (int t = 0; t < 24; ++t) {
    int cur = t & 1;
    COMPUTE(cur);
    BAR();
    if (t < 22) { STAGE(t + 2, cur); WAITV(10); }
    else { WAITV(0); }
    BAR();
  }

#pragma unroll
  for (int mf = 0; mf < 4; ++mf) {
    int prow0 = r0 + wm * 64 + mf * 16 + kq * 4;
#pragma unroll
    for (int nf = 0; nf < 6; ++nf) {
      int col = cb0 + wn * 96 + nf * 16 + l15;
#pragma unroll
      for (int e = 0; e < 4; ++e) {
        int p = prow0 + e;
        out[nat_row(p) * 768 + col] = acc[mf][nf][e] + g_term[(p >> 12) * 768 + col];
      }
    }
  }
}

// ============ G3: combine global-attn partials -> og_mean (B x 768) ============
__global__ void k_greduce(const float* __restrict__ qkv_g,
                          const float* __restrict__ part,
                          float* __restrict__ og_mean) {
  __shared__ float red[4][64];
  int bh = blockIdx.x;
  int b = bh / 12, h = bh - b * 12;
  int tid = threadIdx.x;
  int qi = tid >> 6, d = tid & 63;
  float M = -1e30f, L = 0.f, A = 0.f;
  float qd = qkv_g[qi * 2304 + h * 64 + d];
#pragma unroll
  for (int gk = 0; gk < 4; ++gk) {
    float kd = qkv_g[gk * 2304 + 768 + h * 64 + d];
    float prod = qd * kd;
#pragma unroll
    for (int o = 1; o < 64; o <<= 1) prod += __shfl_xor(prod, o);
    float s = prod * SCALE;
    float Mn = fmaxf(M, s);
    float f = expf(M - Mn), e = expf(s - Mn);
    float vd = qkv_g[gk * 2304 + 1536 + h * 64 + d];
    A = A * f + e * vd;
    L = L * f + e;
    M = Mn;
  }
  for (int p = 0; p < 64; ++p) {
    int pbase = ((b * 12 + h) * 64 + p) * 272;
    float mp = part[pbase + 256 + qi];
    float lp = part[pbase + 260 + qi];
    float ap = part[pbase + qi * 64 + d];
    float Mn = fmaxf(M, mp);
    float f = expf(M - Mn), e = expf(mp - Mn);
    A = A * f + ap * e;
    L = L * f + lp * e;
    M = Mn;
  }
  red[qi][d] = A / L;
  __syncthreads();
  if (tid < 64) {
    float s = (red[0][d] + red[1][d] + red[2][d] + red[3][d]) * 0.25f;
    og_mean[b * 768 + h * 64 + d] = s;
  }
}

// ============ G4: g_term = og_mean @ w_out (B x 768), fp32 ============
__global__ void k_gterm(const float* __restrict__ og_mean,
                        const float* __restrict__ w_out,
                        float* __restrict__ g_term) {
  int idx = blockIdx.x * 256 + threadIdx.x;   // 0..6143
  int b = idx / 768, c = idx - b * 768;
  const float* op = og_mean + b * 768;
  float s = 0.f;
  for (int d = 0; d < 768; ++d) s += op[d] * w_out[d * 768 + c];
  g_term[idx] = s;
}

extern "C" void kernel_launch(void* const* d_in, const int* in_sizes, int n_in,
                              void* d_out, int out_size, void* d_ws, size_t ws_size,
                              hipStream_t stream) {
  const float* x      = (const float*)d_in[0];
  const float* w_qkv  = (const float*)d_in[1];
  const float* w_out  = (const float*)d_in[2];
  const float* qnw    = (const float*)d_in[3];
  const float* knw    = (const float*)d_in[4];
  const float* gtok   = (const float*)d_in[5];
  float* out = (float*)d_out;

  // ---- ws layout (~117 MB) ----
  ushort* WhiQ = (ushort*)d_ws;                 // 2304*768
  ushort* WloQ = WhiQ + 2304 * 768;
  ushort* WhiO = WloQ + 2304 * 768;             // 768*768
  ushort* WloO = WhiO + 768 * 768;
  ushort* o_hi = WloO + 768 * 768;              // 32768*768
  ushort* o_lo = o_hi + 32768 * 768;
  float* qkv_g   = (float*)(o_lo + 32768 * 768);
  float* part    = qkv_g + 9216;                // 8*12*64*272
  float* og_mean = part + 8 * 12 * 64 * 272;
  float* g_term  = og_mean + 6144;

  // x hi/lo planes live in d_out until the final projection overwrites it
  ushort* xh = (ushort*)d_out;                  // 32768*768
  ushort* xl = xh + 32768 * 768;

  k_prep  <<<dim3(36, 12), 256, 0, stream>>>(w_qkv, 2304, 0, WhiQ, WloQ);
  k_prep  <<<dim3(12, 12), 256, 0, stream>>>(w_out,  768, 1, WhiO, WloO);
  k_gqkv  <<<36,    256, 0, stream>>>(gtok, w_qkv, qkv_g);
  k_xsplit<<<12288, 256, 0, stream>>>(x, xh, xl);

  k_fused <<<3072, 256, 0, stream>>>(xh, xl, WhiQ, WloQ, qnw, knw, qkv_g, part, o_hi, o_lo);

  k_greduce<<<96, 256, 0, stream>>>(qkv_g, part, og_mean);
  k_gterm  <<<24, 256, 0, stream>>>(og_mean, w_out, g_term);
  k_proj8 <<<1024, 256, 0, stream>>>(o_hi, o_lo, WhiO, WloO, g_term, out);
}

// Round 13
// 655.330 us; speedup vs baseline: 1.0530x; 1.0530x over previous
//
#include <hip/hip_runtime.h>
#include <hip/hip_bf16.h>

typedef short short8 __attribute__((ext_vector_type(8)));
typedef unsigned short ushort8 __attribute__((ext_vector_type(8)));
typedef unsigned short ushort4v __attribute__((ext_vector_type(4)));
typedef float f32x4 __attribute__((ext_vector_type(4)));
typedef unsigned short ushort;

constexpr float SCALE = 0.125f;   // 64^-0.5
constexpr float EPS_RMS = 1e-6f;

#define BAR() asm volatile("s_barrier" ::: "memory")
#define WAITV(N) asm volatile("s_waitcnt vmcnt(" #N ")" ::: "memory")

__device__ __forceinline__ ushort f2bf(float f) {
  return __builtin_bit_cast(unsigned short, __float2bfloat16(f));
}
__device__ __forceinline__ float bf2f(ushort u) {
  return __bfloat162float(__builtin_bit_cast(__hip_bfloat16, u));
}
__device__ __forceinline__ void gl_lds16(const void* g, void* l) {
  __builtin_amdgcn_global_load_lds((const __attribute__((address_space(1))) void*)g,
                                   (__attribute__((address_space(3))) void*)l, 16, 0, 0);
}

// permuted row p -> natural token row
__device__ __forceinline__ int nat_row(int p) {
  return (p & ~4095) | (((p >> 9) & 7) << 9) | (((p >> 3) & 7) << 6) |
         (((p >> 6) & 7) << 3) | (p & 7);
}

// ============ P0: transpose + split weights into bf16 hi/lo planes ============
__global__ void k_prep(const float* __restrict__ src, int src_ld, int mode,
                       ushort* __restrict__ hi, ushort* __restrict__ lo) {
  __shared__ float tile[64][65];
  int rb = blockIdx.x, db = blockIdx.y;
  int tid = threadIdx.x;
#pragma unroll
  for (int e = 0; e < 16; ++e) {
    int idx = e * 256 + tid;
    int dd = idx >> 6, cc = idx & 63;
    int sc;
    if (mode == 0) { int h = rb / 3, p = rb % 3; sc = p * 768 + h * 64 + cc; }
    else sc = rb * 64 + cc;
    tile[dd][cc] = src[(db * 64 + dd) * src_ld + sc];
  }
  __syncthreads();
#pragma unroll
  for (int e = 0; e < 16; ++e) {
    int idx = e * 256 + tid;
    int cc = idx >> 6, dd = idx & 63;
    float f = tile[dd][cc];
    ushort h = f2bf(f);
    ushort l = f2bf(f - bf2f(h));
    int o = (rb * 64 + cc) * 768 + db * 64 + dd;
    hi[o] = h;
    lo[o] = l;
  }
}

// ============ X: split x into bf16 hi/lo planes, window-permuted rows ============
__global__ void k_xsplit(const float* __restrict__ x,
                         ushort* __restrict__ xh, ushort* __restrict__ xl) {
  int idx = blockIdx.x * 256 + threadIdx.x;   // 32768*96
  int p = idx / 96, seg = idx - p * 96;
  int n = nat_row(p);
  const float* src = x + n * 768 + seg * 8;
  float4 a = *(const float4*)src;
  float4 c = *(const float4*)(src + 4);
  float v[8] = {a.x, a.y, a.z, a.w, c.x, c.y, c.z, c.w};
  ushort8 hi, lo;
#pragma unroll
  for (int j = 0; j < 8; ++j) {
    ushort h = f2bf(v[j]);
    hi[j] = h;
    lo[j] = f2bf(v[j] - bf2f(h));
  }
  *(ushort8*)&xh[p * 768 + seg * 8] = hi;
  *(ushort8*)&xl[p * 768 + seg * 8] = lo;
}

// ============ G1: QKV of the 4 global tokens (4 x 2304), fp32 ============
__global__ void k_gqkv(const float* __restrict__ gtok,
                       const float* __restrict__ w_qkv,
                       float* __restrict__ qkv_g) {
  int idx = blockIdx.x * 256 + threadIdx.x;   // 0..9215
  int tok = idx / 2304, c = idx - tok * 2304;
  const float* gp = gtok + tok * 768;
  float s = 0.f;
  for (int d = 0; d < 768; ++d) s += gp[d] * w_qkv[d * 2304 + c];
  qkv_g[idx] = s;
}

// attention LDS layout (float offsets, stride 68 = 17 float4 units)
#define QS_OFF 0        // q rows [64][68]   (aliased as P after softmax)
#define KT_OFF 4352     // k^T    [64(d)][68(tok)]  (RAW k, transposed)
#define VS_OFF 8704     // v rows [64][68]
#define SQ_OFF 13056    // sq[64]
#define SK_OFF 13120    // sk[64]
#define PC_OFF 13248    // ps_c[256]

// ============ F: fused QKV-GEMM (128x192, 4-plane BK=32) + attention ============
// 256 threads (4 waves), 80KB LDS -> 2 blocks/CU. Attention is the register-light
// 2x4 half-tile version (fits the 128 arch-VGPR budget left by live AGPR acc).
__global__ __launch_bounds__(256, 2) void k_fused(
    const ushort* __restrict__ xh, const ushort* __restrict__ xl,
    const ushort* __restrict__ Whi, const ushort* __restrict__ Wlo,
    const float* __restrict__ qnw, const float* __restrict__ knw,
    const float* __restrict__ qkv_g, float* __restrict__ part,
    ushort* __restrict__ o_hi, ushort* __restrict__ o_lo) {
  __shared__ __align__(16) char smem[81920];   // GEMM: 2 x 40KB ; attn: 54KB
  const int tid = threadIdx.x;
  const int lane = tid & 63;
  const int wv = tid >> 6;                     // 0..3
  const int wm = wv >> 1, wn = wv & 1;         // 2M x 2N, wave tile 64x96
  const int l15 = lane & 15, kq = lane >> 4;
  const int bid = blockIdx.x;
  const int xcd = bid & 7, kk_ = bid >> 3;
  const int h = kk_ % 12;
  const int mblk = (kk_ / 12) * 8 + xcd;       // 0..255
  const int r0 = mblk * 128;
  const int cb0 = h * 192;

  // staging maps: A region 16KB (Ah|Al), B region 24KB (Bh|Bl), 16B/thread-load
  int gAo[4], lA[4]; bool pA[4];
#pragma unroll
  for (int j = 0; j < 4; ++j) {
    int byo = (j * 256 + tid) * 16;            // 0..16383
    pA[j] = byo >= 8192;
    int wb = byo & 8191;
    int row = wb >> 6, sl = (wb >> 4) & 3;
    int kb = sl ^ ((row >> 1) & 3);
    gAo[j] = (r0 + row) * 768 + kb * 8;
    lA[j] = byo;
  }
  int gBo[6], lB[6]; bool pB[6];
#pragma unroll
  for (int j = 0; j < 6; ++j) {
    int byo = (j * 256 + tid) * 16;            // 0..24575
    pB[j] = byo >= 12288;
    int wb = pB[j] ? byo - 12288 : byo;
    int row = wb >> 6, sl = (wb >> 4) & 3;
    int kb = sl ^ ((row >> 1) & 3);
    gBo[j] = (cb0 + row) * 768 + kb * 8;
    lB[j] = 16384 + byo;
  }

  f32x4 acc[4][6];
#pragma unroll
  for (int i = 0; i < 4; ++i)
#pragma unroll
    for (int j = 0; j < 6; ++j) acc[i][j] = (f32x4){0.f, 0.f, 0.f, 0.f};

  auto STAGE = [&](int t, int bufi) {
    const int kk = t * 32;
    char* bb = smem + bufi * 40960;
#pragma unroll
    for (int j = 0; j < 4; ++j) {
      const ushort* Ap = pA[j] ? xl : xh;
      gl_lds16(Ap + gAo[j] + kk, bb + lA[j]);
    }
#pragma unroll
    for (int j = 0; j < 6; ++j) {
      const ushort* Bp = pB[j] ? Wlo : Whi;
      gl_lds16(Bp + gBo[j] + kk, bb + lB[j]);
    }
  };

  auto COMPUTE = [&](int bufi) {
    const char* ba = smem + bufi * 40960;
    short8 ah[4], al[4], bh[6], bl[6];
#pragma unroll
    for (int mf = 0; mf < 4; ++mf) {
      int row = wm * 64 + mf * 16 + l15;
      int so = (kq ^ ((row >> 1) & 3)) << 4;
      ah[mf] = *(const short8*)(ba + row * 64 + so);
      al[mf] = *(const short8*)(ba + 8192 + row * 64 + so);
    }
#pragma unroll
    for (int nf = 0; nf < 6; ++nf) {
      int row = wn * 96 + nf * 16 + l15;
      int so = (kq ^ ((row >> 1) & 3)) << 4;
      bh[nf] = *(const short8*)(ba + 16384 + row * 64 + so);
      bl[nf] = *(const short8*)(ba + 28672 + row * 64 + so);
    }
    __builtin_amdgcn_s_setprio(1);
#pragma unroll
    for (int mf = 0; mf < 4; ++mf)
#pragma unroll
      for (int nf = 0; nf < 6; ++nf) {
        acc[mf][nf] = __builtin_amdgcn_mfma_f32_16x16x32_bf16(ah[mf], bh[nf], acc[mf][nf], 0, 0, 0);
        acc[mf][nf] = __builtin_amdgcn_mfma_f32_16x16x32_bf16(ah[mf], bl[nf], acc[mf][nf], 0, 0, 0);
        acc[mf][nf] = __builtin_amdgcn_mfma_f32_16x16x32_bf16(al[mf], bh[nf], acc[mf][nf], 0, 0, 0);
      }
    __builtin_amdgcn_s_setprio(0);
  };

  STAGE(0, 0); STAGE(1, 1);
  WAITV(10); BAR();
  for (int t = 0; t < 24; ++t) {
    int cur = t & 1;
    COMPUTE(cur);
    BAR();
    if (t < 22) { STAGE(t + 2, cur); WAITV(10); }
    else { WAITV(0); }
    BAR();
  }

  // ======== attention: 2 passes x 1 window; 2x4 half-tiles, f32x4 LDS ========
  const int tl = tid;
  float* gb = (float*)smem;
  for (int pass = 0; pass < 2; ++pass) {
    // scatter this pass's window (waves with wm==pass): q rows, k^T (raw), v rows
    if (wm == pass) {
#pragma unroll
      for (int mf = 0; mf < 4; ++mf) {
#pragma unroll
        for (int nf = 0; nf < 6; ++nf) {
          int col = wn * 96 + nf * 16 + l15;
#pragma unroll
          for (int e = 0; e < 4; ++e) {
            int tok = mf * 16 + kq * 4 + e;
            float val = acc[mf][nf][e];
            if (col < 64)       gb[QS_OFF + tok * 68 + col] = val;
            else if (col < 128) gb[KT_OFF + (col - 64) * 68 + tok] = val;
            else                gb[VS_OFF + tok * 68 + (col - 128)] = val;
          }
        }
      }
    }
    __syncthreads();

    const int widx = mblk * 2 + pass;
    const int b = widx >> 6, wl = widx & 63;

    // ---- phase C: global-attn partials (raw k^T, raw v) ----
    {
      int qi = tl >> 6, j = tl & 63;
      const float* qgp = qkv_g + qi * 2304 + h * 64;
      float s = 0.f;
#pragma unroll 16
      for (int d = 0; d < 64; ++d) s += qgp[d] * gb[KT_OFF + d * 68 + j];
      s *= SCALE;
      float m = s;
#pragma unroll
      for (int o = 1; o < 64; o <<= 1) m = fmaxf(m, __shfl_xor(m, o));
      float p = __expf(s - m);
      float l = p;
#pragma unroll
      for (int o = 1; o < 64; o <<= 1) l += __shfl_xor(l, o);
      gb[PC_OFF + qi * 64 + j] = p;
      int pbase = ((b * 12 + h) * 64 + wl) * 272;
      if (j == 0) { part[pbase + 256 + qi] = m; part[pbase + 260 + qi] = l; }
      __syncthreads();
      float a = 0.f;
#pragma unroll
      for (int j4 = 0; j4 < 16; ++j4) {
        f32x4 pc = *(const f32x4*)&gb[PC_OFF + qi * 64 + j4 * 4];
        a += pc[0] * gb[VS_OFF + (j4 * 4 + 0) * 68 + j] +
             pc[1] * gb[VS_OFF + (j4 * 4 + 1) * 68 + j] +
             pc[2] * gb[VS_OFF + (j4 * 4 + 2) * 68 + j] +
             pc[3] * gb[VS_OFF + (j4 * 4 + 3) * 68 + j];
      }
      part[pbase + qi * 64 + j] = a;
    }
    __syncthreads();

    // ---- rms scales: sq from q rows (f32x4), sk from kT cols ----
    if (tl < 64) {
      float ss = 0.f;
#pragma unroll
      for (int d4 = 0; d4 < 16; ++d4) {
        f32x4 v = *(const f32x4*)&gb[QS_OFF + tl * 68 + d4 * 4];
        ss += v[0] * v[0] + v[1] * v[1] + v[2] * v[2] + v[3] * v[3];
      }
      gb[SQ_OFF + tl] = 1.0f / sqrtf(ss * 0.015625f + EPS_RMS);
    } else if (tl < 128) {
      int c = tl - 64;
      float ss = 0.f;
#pragma unroll 16
      for (int d = 0; d < 64; ++d) { float t = gb[KT_OFF + d * 68 + c]; ss += t * t; }
      gb[SK_OFF + c] = 1.0f / sqrtf(ss * 0.015625f + EPS_RMS);
    }
    __syncthreads();

    // ---- phase B: local attention, 2x4 half-tiles (register-light) ----
    {
      const int ty = tl >> 4, tx = tl & 15;
      const int c0k = tx * 4;
      const f32x4* qnw4 = (const f32x4*)qnw;
      const f32x4* knw4 = (const f32x4*)knw;
      const f32x4 skv = *(const f32x4*)&gb[SK_OFF + c0k];
#pragma unroll
      for (int half = 0; half < 2; ++half) {
        const int r0q = ty * 4 + half * 2;   // rows r0q, r0q+1 (ty-private)
        const float sq0 = gb[SQ_OFF + r0q];
        const float sq1 = gb[SQ_OFF + r0q + 1];
        f32x4 X0 = {0.f, 0.f, 0.f, 0.f}, X1 = {0.f, 0.f, 0.f, 0.f};
#pragma unroll
        for (int d4 = 0; d4 < 16; ++d4) {
          f32x4 ww = qnw4[d4] * knw4[d4];
          f32x4 q0 = *(const f32x4*)&gb[QS_OFF + r0q * 68 + d4 * 4];
          f32x4 q1 = *(const f32x4*)&gb[QS_OFF + (r0q + 1) * 68 + d4 * 4];
          q0 *= ww; q1 *= ww;
          f32x4 k0 = *(const f32x4*)&gb[KT_OFF + (d4 * 4 + 0) * 68 + c0k];
          f32x4 k1 = *(const f32x4*)&gb[KT_OFF + (d4 * 4 + 1) * 68 + c0k];
          f32x4 k2 = *(const f32x4*)&gb[KT_OFF + (d4 * 4 + 2) * 68 + c0k];
          f32x4 k3 = *(const f32x4*)&gb[KT_OFF + (d4 * 4 + 3) * 68 + c0k];
          X0 += q0[0] * k0 + q0[1] * k1 + q0[2] * k2 + q0[3] * k3;
          X1 += q1[0] * k0 + q1[1] * k1 + q1[2] * k2 + q1[3] * k3;
        }
        X0 = X0 * skv * (sq0 * SCALE);
        X1 = X1 * skv * (sq1 * SCALE);
        float m0 = fmaxf(fmaxf(X0[0], X0[1]), fmaxf(X0[2], X0[3]));
        float m1 = fmaxf(fmaxf(X1[0], X1[1]), fmaxf(X1[2], X1[3]));
#pragma unroll
        for (int o = 1; o < 16; o <<= 1) {
          m0 = fmaxf(m0, __shfl_xor(m0, o));
          m1 = fmaxf(m1, __shfl_xor(m1, o));
        }
        f32x4 P0, P1;
#pragma unroll
        for (int cc = 0; cc < 4; ++cc) {
          P0[cc] = __expf(X0[cc] - m0);
          P1[cc] = __expf(X1[cc] - m1);
        }
        float s0 = P0[0] + P0[1] + P0[2] + P0[3];
        float s1 = P1[0] + P1[1] + P1[2] + P1[3];
#pragma unroll
        for (int o = 1; o < 16; o <<= 1) {
          s0 += __shfl_xor(s0, o);
          s1 += __shfl_xor(s1, o);
        }
        const float li0 = 1.0f / s0, li1 = 1.0f / s1;
        // P overwrites q rows r0q/r0q+1: ty-private rows, same-wave lockstep
        *(f32x4*)&gb[QS_OFF + r0q * 68 + c0k] = P0;
        *(f32x4*)&gb[QS_OFF + (r0q + 1) * 68 + c0k] = P1;
        f32x4 O0 = {0.f, 0.f, 0.f, 0.f}, O1 = {0.f, 0.f, 0.f, 0.f};
#pragma unroll
        for (int j4 = 0; j4 < 16; ++j4) {
          f32x4 p0 = *(const f32x4*)&gb[QS_OFF + r0q * 68 + j4 * 4];
          f32x4 p1 = *(const f32x4*)&gb[QS_OFF + (r0q + 1) * 68 + j4 * 4];
          f32x4 v0 = *(const f32x4*)&gb[VS_OFF + (j4 * 4 + 0) * 68 + c0k];
          f32x4 v1 = *(const f32x4*)&gb[VS_OFF + (j4 * 4 + 1) * 68 + c0k];
          f32x4 v2 = *(const f32x4*)&gb[VS_OFF + (j4 * 4 + 2) * 68 + c0k];
          f32x4 v3 = *(const f32x4*)&gb[VS_OFF + (j4 * 4 + 3) * 68 + c0k];
          O0 += p0[0] * v0 + p0[1] * v1 + p0[2] * v2 + p0[3] * v3;
          O1 += p1[0] * v0 + p1[1] * v1 + p1[2] * v2 + p1[3] * v3;
        }
        O0 *= li0;
        O1 *= li1;
        int orow0 = (widx * 64 + r0q) * 768 + h * 64 + c0k;
        ushort4v h0, l0, h1, l1;
#pragma unroll
        for (int cc = 0; cc < 4; ++cc) {
          float a0 = O0[cc]; ushort hh0 = f2bf(a0);
          h0[cc] = hh0; l0[cc] = f2bf(a0 - bf2f(hh0));
          float a1 = O1[cc]; ushort hh1 = f2bf(a1);
          h1[cc] = hh1; l1[cc] = f2bf(a1 - bf2f(hh1));
        }
        *(ushort4v*)&o_hi[orow0] = h0;
        *(ushort4v*)&o_lo[orow0] = l0;
        *(ushort4v*)&o_hi[orow0 + 768] = h1;
        *(ushort4v*)&o_lo[orow0 + 768] = l1;
      }
    }
    __syncthreads();
  }
}

// ============ P: projection out = o @ w_out + g_term (128x192, 4-plane BK=32) ====
// 256 threads, 80KB LDS -> 2 blocks/CU. grid = 1024, XCD-local decode.
__global__ __launch_bounds__(256, 2) void k_proj8(
    const ushort* __restrict__ o_hi, const ushort* __restrict__ o_lo,
    const ushort* __restrict__ Whi, const ushort* __restrict__ Wlo,
    const float* __restrict__ g_term, float* __restrict__ out) {
  __shared__ __align__(16) char smem[81920];
  const int tid = threadIdx.x;
  const int lane = tid & 63;
  const int wv = tid >> 6;
  const int wm = wv >> 1, wn = wv & 1;
  const int l15 = lane & 15, kq = lane >> 4;
  const int bid = blockIdx.x;
  const int xcd = bid & 7, kk_ = bid >> 3;     // 0..127
  const int cblk = kk_ % 4;
  const int mblk = (kk_ / 4) * 8 + xcd;        // 0..255
  const int r0 = mblk * 128;
  const int cb0 = cblk * 192;

  int gAo[4], lA[4]; bool pA[4];
#pragma unroll
  for (int j = 0; j < 4; ++j) {
    int byo = (j * 256 + tid) * 16;
    pA[j] = byo >= 8192;
    int wb = byo & 8191;
    int row = wb >> 6, sl = (wb >> 4) & 3;
    int kb = sl ^ ((row >> 1) & 3);
    gAo[j] = (r0 + row) * 768 + kb * 8;
    lA[j] = byo;
  }
  int gBo[6], lB[6]; bool pB[6];
#pragma unroll
  for (int j = 0; j < 6; ++j) {
    int byo = (j * 256 + tid) * 16;
    pB[j] = byo >= 12288;
    int wb = pB[j] ? byo - 12288 : byo;
    int row = wb >> 6, sl = (wb >> 4) & 3;
    int kb = sl ^ ((row >> 1) & 3);
    gBo[j] = (cb0 + row) * 768 + kb * 8;
    lB[j] = 16384 + byo;
  }

  f32x4 acc[4][6];
#pragma unroll
  for (int i = 0; i < 4; ++i)
#pragma unroll
    for (int j = 0; j < 6; ++j) acc[i][j] = (f32x4){0.f, 0.f, 0.f, 0.f};

  auto STAGE = [&](int t, int bufi) {
    const int kk = t * 32;
    char* bb = smem + bufi * 40960;
#pragma unroll
    for (int j = 0; j < 4; ++j) {
      const ushort* Ap = pA[j] ? o_lo : o_hi;
      gl_lds16(Ap + gAo[j] + kk, bb + lA[j]);
    }
#pragma unroll
    for (int j = 0; j < 6; ++j) {
      const ushort* Bp = pB[j] ? Wlo : Whi;
      gl_lds16(Bp + gBo[j] + kk, bb + lB[j]);
    }
  };

  auto COMPUTE = [&](int bufi) {
    const char* ba = smem + bufi * 40960;
    short8 ah[4], al[4], bh[6], bl[6];
#pragma unroll
    for (int mf = 0; mf < 4; ++mf) {
      int row = wm * 64 + mf * 16 + l15;
      int so = (kq ^ ((row >> 1) & 3)) << 4;
      ah[mf] = *(const short8*)(ba + row * 64 + so);
      al[mf] = *(const short8*)(ba + 8192 + row * 64 + so);
    }
#pragma unroll
    for (int nf = 0; nf < 6; ++nf) {
      int row = wn * 96 + nf * 16 + l15;
      int so = (kq ^ ((row >> 1) & 3)) << 4;
      bh[nf] = *(const short8*)(ba + 16384 + row * 64 + so);
      bl[nf] = *(const short8*)(ba + 28672 + row * 64 + so);
    }
    __builtin_amdgcn_s_setprio(1);
#pragma unroll
    for (int mf = 0; mf < 4; ++mf)
#pragma unroll
      for (int nf = 0; nf < 6; ++nf) {
        acc[mf][nf] = __builtin_amdgcn_mfma_f32_16x16x32_bf16(ah[mf], bh[nf], acc[mf][nf], 0, 0, 0);
        acc[mf][nf] = __builtin_amdgcn_mfma_f32_16x16x32_bf16(ah[mf], bl[nf], acc[mf][nf], 0, 0, 0);
        acc[mf][nf] = __builtin_amdgcn_mfma_f32_16x16x32_bf16(al[mf], bh[nf], acc[mf][nf], 0, 0, 0);
      }
    __builtin_amdgcn_s_setprio(0);
  };

  STAGE(0, 0); STAGE(1, 1);
  WAITV(10); BAR();
  for (int t = 0; t < 24; ++t) {
    int cur = t & 1;
    COMPUTE(cur);
    BAR();
    if (t < 22) { STAGE(t + 2, cur); WAITV(10); }
    else { WAITV(0); }
    BAR();
  }

#pragma unroll
  for (int mf = 0; mf < 4; ++mf) {
    int prow0 = r0 + wm * 64 + mf * 16 + kq * 4;
#pragma unroll
    for (int nf = 0; nf < 6; ++nf) {
      int col = cb0 + wn * 96 + nf * 16 + l15;
#pragma unroll
      for (int e = 0; e < 4; ++e) {
        int p = prow0 + e;
        out[nat_row(p) * 768 + col] = acc[mf][nf][e] + g_term[(p >> 12) * 768 + col];
      }
    }
  }
}

// ============ G3: combine global-attn partials -> og_mean (B x 768) ============
__global__ void k_greduce(const float* __restrict__ qkv_g,
                          const float* __restrict__ part,
                          float* __restrict__ og_mean) {
  __shared__ float red[4][64];
  int bh = blockIdx.x;
  int b = bh / 12, h = bh - b * 12;
  int tid = threadIdx.x;
  int qi = tid >> 6, d = tid & 63;
  float M = -1e30f, L = 0.f, A = 0.f;
  float qd = qkv_g[qi * 2304 + h * 64 + d];
#pragma unroll
  for (int gk = 0; gk < 4; ++gk) {
    float kd = qkv_g[gk * 2304 + 768 + h * 64 + d];
    float prod = qd * kd;
#pragma unroll
    for (int o = 1; o < 64; o <<= 1) prod += __shfl_xor(prod, o);
    float s = prod * SCALE;
    float Mn = fmaxf(M, s);
    float f = __expf(M - Mn), e = __expf(s - Mn);
    float vd = qkv_g[gk * 2304 + 1536 + h * 64 + d];
    A = A * f + e * vd;
    L = L * f + e;
    M = Mn;
  }
  for (int p = 0; p < 64; ++p) {
    int pbase = ((b * 12 + h) * 64 + p) * 272;
    float mp = part[pbase + 256 + qi];
    float lp = part[pbase + 260 + qi];
    float ap = part[pbase + qi * 64 + d];
    float Mn = fmaxf(M, mp);
    float f = __expf(M - Mn), e = __expf(mp - Mn);
    A = A * f + ap * e;
    L = L * f + lp * e;
    M = Mn;
  }
  red[qi][d] = A / L;
  __syncthreads();
  if (tid < 64) {
    float s = (red[0][d] + red[1][d] + red[2][d] + red[3][d]) * 0.25f;
    og_mean[b * 768 + h * 64 + d] = s;
  }
}

// ============ G4: g_term = og_mean @ w_out (B x 768), fp32 ============
__global__ void k_gterm(const float* __restrict__ og_mean,
                        const float* __restrict__ w_out,
                        float* __restrict__ g_term) {
  int idx = blockIdx.x * 256 + threadIdx.x;   // 0..6143
  int b = idx / 768, c = idx - b * 768;
  const float* op = og_mean + b * 768;
  float s = 0.f;
  for (int d = 0; d < 768; ++d) s += op[d] * w_out[d * 768 + c];
  g_term[idx] = s;
}

extern "C" void kernel_launch(void* const* d_in, const int* in_sizes, int n_in,
                              void* d_out, int out_size, void* d_ws, size_t ws_size,
                              hipStream_t stream) {
  const float* x      = (const float*)d_in[0];
  const float* w_qkv  = (const float*)d_in[1];
  const float* w_out  = (const float*)d_in[2];
  const float* qnw    = (const float*)d_in[3];
  const float* knw    = (const float*)d_in[4];
  const float* gtok   = (const float*)d_in[5];
  float* out = (float*)d_out;

  // ---- ws layout (~117 MB) ----
  ushort* WhiQ = (ushort*)d_ws;                 // 2304*768
  ushort* WloQ = WhiQ + 2304 * 768;
  ushort* WhiO = WloQ + 2304 * 768;             // 768*768
  ushort* WloO = WhiO + 768 * 768;
  ushort* o_hi = WloO + 768 * 768;              // 32768*768
  ushort* o_lo = o_hi + 32768 * 768;
  float* qkv_g   = (float*)(o_lo + 32768 * 768);
  float* part    = qkv_g + 9216;                // 8*12*64*272
  float* og_mean = part + 8 * 12 * 64 * 272;
  float* g_term  = og_mean + 6144;

  // x hi/lo planes live in d_out until the final projection overwrites it
  ushort* xh = (ushort*)d_out;                  // 32768*768
  ushort* xl = xh + 32768 * 768;

  k_prep  <<<dim3(36, 12), 256, 0, stream>>>(w_qkv, 2304, 0, WhiQ, WloQ);
  k_prep  <<<dim3(12, 12), 256, 0, stream>>>(w_out,  768, 1, WhiO, WloO);
  k_gqkv  <<<36,    256, 0, stream>>>(gtok, w_qkv, qkv_g);
  k_xsplit<<<12288, 256, 0, stream>>>(x, xh, xl);

  k_fused <<<3072, 256, 0, stream>>>(xh, xl, WhiQ, WloQ, qnw, knw, qkv_g, part, o_hi, o_lo);

  k_greduce<<<96, 256, 0, stream>>>(qkv_g, part, og_mean);
  k_gterm  <<<24, 256, 0, stream>>>(og_mean, w_out, g_term);
  k_proj8 <<<1024, 256, 0, stream>>>(o_hi, o_lo, WhiO, WloO, g_term, out);
}

// Round 14
// 654.863 us; speedup vs baseline: 1.0538x; 1.0007x over previous
//
#include <hip/hip_runtime.h>
#include <hip/hip_bf16.h>

typedef short short8 __attribute__((ext_vector_type(8)));
typedef unsigned short ushort8 __attribute__((ext_vector_type(8)));
typedef unsigned short ushort4v __attribute__((ext_vector_type(4)));
typedef float f32x4 __attribute__((ext_vector_type(4)));
typedef unsigned short ushort;

constexpr float SCALE = 0.125f;   // 64^-0.5
constexpr float EPS_RMS = 1e-6f;

#define BAR() asm volatile("s_barrier" ::: "memory")
#define WAITV(N) asm volatile("s_waitcnt vmcnt(" #N ")" ::: "memory")

__device__ __forceinline__ ushort f2bf(float f) {
  return __builtin_bit_cast(unsigned short, __float2bfloat16(f));
}
__device__ __forceinline__ float bf2f(ushort u) {
  return __bfloat162float(__builtin_bit_cast(__hip_bfloat16, u));
}
__device__ __forceinline__ void gl_lds16(const void* g, void* l) {
  __builtin_amdgcn_global_load_lds((const __attribute__((address_space(1))) void*)g,
                                   (__attribute__((address_space(3))) void*)l, 16, 0, 0);
}

// permuted row p -> natural token row
__device__ __forceinline__ int nat_row(int p) {
  return (p & ~4095) | (((p >> 9) & 7) << 9) | (((p >> 3) & 7) << 6) |
         (((p >> 6) & 7) << 3) | (p & 7);
}

// ============ P0: transpose + split weights into bf16 hi/lo planes ============
__global__ void k_prep(const float* __restrict__ src, int src_ld, int mode,
                       ushort* __restrict__ hi, ushort* __restrict__ lo) {
  __shared__ float tile[64][65];
  int rb = blockIdx.x, db = blockIdx.y;
  int tid = threadIdx.x;
#pragma unroll
  for (int e = 0; e < 16; ++e) {
    int idx = e * 256 + tid;
    int dd = idx >> 6, cc = idx & 63;
    int sc;
    if (mode == 0) { int h = rb / 3, p = rb % 3; sc = p * 768 + h * 64 + cc; }
    else sc = rb * 64 + cc;
    tile[dd][cc] = src[(db * 64 + dd) * src_ld + sc];
  }
  __syncthreads();
#pragma unroll
  for (int e = 0; e < 16; ++e) {
    int idx = e * 256 + tid;
    int cc = idx >> 6, dd = idx & 63;
    float f = tile[dd][cc];
    ushort h = f2bf(f);
    ushort l = f2bf(f - bf2f(h));
    int o = (rb * 64 + cc) * 768 + db * 64 + dd;
    hi[o] = h;
    lo[o] = l;
  }
}

// ============ X: split x into bf16 hi/lo planes, window-permuted rows ============
__global__ void k_xsplit(const float* __restrict__ x,
                         ushort* __restrict__ xh, ushort* __restrict__ xl) {
  int idx = blockIdx.x * 256 + threadIdx.x;   // 32768*96
  int p = idx / 96, seg = idx - p * 96;
  int n = nat_row(p);
  const float* src = x + n * 768 + seg * 8;
  float4 a = *(const float4*)src;
  float4 c = *(const float4*)(src + 4);
  float v[8] = {a.x, a.y, a.z, a.w, c.x, c.y, c.z, c.w};
  ushort8 hi, lo;
#pragma unroll
  for (int j = 0; j < 8; ++j) {
    ushort h = f2bf(v[j]);
    hi[j] = h;
    lo[j] = f2bf(v[j] - bf2f(h));
  }
  *(ushort8*)&xh[p * 768 + seg * 8] = hi;
  *(ushort8*)&xl[p * 768 + seg * 8] = lo;
}

// ============ G1: QKV of the 4 global tokens (4 x 2304), fp32 ============
__global__ void k_gqkv(const float* __restrict__ gtok,
                       const float* __restrict__ w_qkv,
                       float* __restrict__ qkv_g) {
  int idx = blockIdx.x * 256 + threadIdx.x;   // 0..9215
  int tok = idx / 2304, c = idx - tok * 2304;
  const float* gp = gtok + tok * 768;
  float s = 0.f;
  for (int d = 0; d < 768; ++d) s += gp[d] * w_qkv[d * 2304 + c];
  qkv_g[idx] = s;
}

// attention LDS layout (float offsets, stride 68 = 17 float4 units)
#define QS_OFF 0        // q rows [64][68]   (aliased as P after softmax)
#define KT_OFF 4352     // k^T    [64(d)][68(tok)]  (RAW k, transposed)
#define VS_OFF 8704     // v rows [64][68]
#define SQ_OFF 13056    // sq[64]
#define SK_OFF 13120    // sk[64]
#define PC_OFF 13248    // ps_c[256]
#define WW_OFF 13504    // qnw*knw [64]  (written pass 0, above scatter region)

// ============ F: fused QKV-GEMM (128x192, 4-plane BK=32) + attention ============
// 256 threads (4 waves), 80KB LDS -> 2 blocks/CU. Attention is the register-light
// 2x4 half-tile version (fits the 128 arch-VGPR budget left by live AGPR acc).
__global__ __launch_bounds__(256, 2) void k_fused(
    const ushort* __restrict__ xh, const ushort* __restrict__ xl,
    const ushort* __restrict__ Whi, const ushort* __restrict__ Wlo,
    const float* __restrict__ qnw, const float* __restrict__ knw,
    const float* __restrict__ qkv_g, float* __restrict__ part,
    ushort* __restrict__ o_hi, ushort* __restrict__ o_lo) {
  __shared__ __align__(16) char smem[81920];   // GEMM: 2 x 40KB ; attn: 54KB
  const int tid = threadIdx.x;
  const int lane = tid & 63;
  const int wv = tid >> 6;                     // 0..3
  const int wm = wv >> 1, wn = wv & 1;         // 2M x 2N, wave tile 64x96
  const int l15 = lane & 15, kq = lane >> 4;
  const int bid = blockIdx.x;
  const int xcd = bid & 7, kk_ = bid >> 3;
  const int h = kk_ % 12;
  const int mblk = (kk_ / 12) * 8 + xcd;       // 0..255
  const int r0 = mblk * 128;
  const int cb0 = h * 192;

  // staging maps: A region 16KB (Ah|Al), B region 24KB (Bh|Bl), 16B/thread-load
  int gAo[4], lA[4]; bool pA[4];
#pragma unroll
  for (int j = 0; j < 4; ++j) {
    int byo = (j * 256 + tid) * 16;            // 0..16383
    pA[j] = byo >= 8192;
    int wb = byo & 8191;
    int row = wb >> 6, sl = (wb >> 4) & 3;
    int kb = sl ^ ((row >> 1) & 3);
    gAo[j] = (r0 + row) * 768 + kb * 8;
    lA[j] = byo;
  }
  int gBo[6], lB[6]; bool pB[6];
#pragma unroll
  for (int j = 0; j < 6; ++j) {
    int byo = (j * 256 + tid) * 16;            // 0..24575
    pB[j] = byo >= 12288;
    int wb = pB[j] ? byo - 12288 : byo;
    int row = wb >> 6, sl = (wb >> 4) & 3;
    int kb = sl ^ ((row >> 1) & 3);
    gBo[j] = (cb0 + row) * 768 + kb * 8;
    lB[j] = 16384 + byo;
  }

  f32x4 acc[4][6];
#pragma unroll
  for (int i = 0; i < 4; ++i)
#pragma unroll
    for (int j = 0; j < 6; ++j) acc[i][j] = (f32x4){0.f, 0.f, 0.f, 0.f};

  auto STAGE = [&](int t, int bufi) {
    const int kk = t * 32;
    char* bb = smem + bufi * 40960;
#pragma unroll
    for (int j = 0; j < 4; ++j) {
      const ushort* Ap = pA[j] ? xl : xh;
      gl_lds16(Ap + gAo[j] + kk, bb + lA[j]);
    }
#pragma unroll
    for (int j = 0; j < 6; ++j) {
      const ushort* Bp = pB[j] ? Wlo : Whi;
      gl_lds16(Bp + gBo[j] + kk, bb + lB[j]);
    }
  };

  auto COMPUTE = [&](int bufi) {
    const char* ba = smem + bufi * 40960;
    short8 ah[4], al[4], bh[6], bl[6];
#pragma unroll
    for (int mf = 0; mf < 4; ++mf) {
      int row = wm * 64 + mf * 16 + l15;
      int so = (kq ^ ((row >> 1) & 3)) << 4;
      ah[mf] = *(const short8*)(ba + row * 64 + so);
      al[mf] = *(const short8*)(ba + 8192 + row * 64 + so);
    }
#pragma unroll
    for (int nf = 0; nf < 6; ++nf) {
      int row = wn * 96 + nf * 16 + l15;
      int so = (kq ^ ((row >> 1) & 3)) << 4;
      bh[nf] = *(const short8*)(ba + 16384 + row * 64 + so);
      bl[nf] = *(const short8*)(ba + 28672 + row * 64 + so);
    }
    __builtin_amdgcn_s_setprio(1);
#pragma unroll
    for (int mf = 0; mf < 4; ++mf)
#pragma unroll
      for (int nf = 0; nf < 6; ++nf) {
        acc[mf][nf] = __builtin_amdgcn_mfma_f32_16x16x32_bf16(ah[mf], bh[nf], acc[mf][nf], 0, 0, 0);
        acc[mf][nf] = __builtin_amdgcn_mfma_f32_16x16x32_bf16(ah[mf], bl[nf], acc[mf][nf], 0, 0, 0);
        acc[mf][nf] = __builtin_amdgcn_mfma_f32_16x16x32_bf16(al[mf], bh[nf], acc[mf][nf], 0, 0, 0);
      }
    __builtin_amdgcn_s_setprio(0);
  };

  STAGE(0, 0); STAGE(1, 1);
  WAITV(10); BAR();
  for (int t = 0; t < 24; ++t) {
    int cur = t & 1;
    COMPUTE(cur);
    BAR();
    if (t < 22) { STAGE(t + 2, cur); WAITV(10); }
    else { WAITV(0); }
    BAR();
  }

  // ======== attention: 2 passes x 1 window; 2x4 half-tiles, f32x4 LDS ========
  const int tl = tid;
  float* gb = (float*)smem;
  for (int pass = 0; pass < 2; ++pass) {
    // scatter this pass's window (waves with wm==pass): q rows, k^T (raw), v rows
    if (wm == pass) {
#pragma unroll
      for (int mf = 0; mf < 4; ++mf) {
#pragma unroll
        for (int nf = 0; nf < 6; ++nf) {
          int col = wn * 96 + nf * 16 + l15;
#pragma unroll
          for (int e = 0; e < 4; ++e) {
            int tok = mf * 16 + kq * 4 + e;
            float val = acc[mf][nf][e];
            if (col < 64)       gb[QS_OFF + tok * 68 + col] = val;
            else if (col < 128) gb[KT_OFF + (col - 64) * 68 + tok] = val;
            else                gb[VS_OFF + tok * 68 + (col - 128)] = val;
          }
        }
      }
    }
    if (pass == 0 && tl < 64) gb[WW_OFF + tl] = qnw[tl] * knw[tl];
    __syncthreads();

    const int widx = mblk * 2 + pass;
    const int b = widx >> 6, wl = widx & 63;

    // ---- phase C (global-attn partials) + rms scales, merged ----
    {
      int qi = tl >> 6, j = tl & 63;
      const f32x4* qgp4 = (const f32x4*)(qkv_g + qi * 2304 + h * 64);
      float s = 0.f;
#pragma unroll
      for (int d4 = 0; d4 < 16; ++d4) {
        f32x4 qg = qgp4[d4];
        s += qg[0] * gb[KT_OFF + (d4 * 4 + 0) * 68 + j] +
             qg[1] * gb[KT_OFF + (d4 * 4 + 1) * 68 + j] +
             qg[2] * gb[KT_OFF + (d4 * 4 + 2) * 68 + j] +
             qg[3] * gb[KT_OFF + (d4 * 4 + 3) * 68 + j];
      }
      s *= SCALE;
      float m = s;
#pragma unroll
      for (int o = 1; o < 64; o <<= 1) m = fmaxf(m, __shfl_xor(m, o));
      float p = __expf(s - m);
      float l = p;
#pragma unroll
      for (int o = 1; o < 64; o <<= 1) l += __shfl_xor(l, o);
      gb[PC_OFF + qi * 64 + j] = p;
      int pbase = ((b * 12 + h) * 64 + wl) * 272;
      if (j == 0) { part[pbase + 256 + qi] = m; part[pbase + 260 + qi] = l; }
      // merged rms scales (read only q rows / kT cols; nothing here writes them)
      if (tl < 64) {
        float ss = 0.f;
#pragma unroll
        for (int d4 = 0; d4 < 16; ++d4) {
          f32x4 v = *(const f32x4*)&gb[QS_OFF + tl * 68 + d4 * 4];
          ss += v[0] * v[0] + v[1] * v[1] + v[2] * v[2] + v[3] * v[3];
        }
        gb[SQ_OFF + tl] = 1.0f / sqrtf(ss * 0.015625f + EPS_RMS);
      } else if (tl < 128) {
        int c = tl - 64;
        float ss = 0.f;
#pragma unroll 16
        for (int d = 0; d < 64; ++d) { float t = gb[KT_OFF + d * 68 + c]; ss += t * t; }
        gb[SK_OFF + c] = 1.0f / sqrtf(ss * 0.015625f + EPS_RMS);
      }
      __syncthreads();
      float a = 0.f;
#pragma unroll
      for (int j4 = 0; j4 < 16; ++j4) {
        f32x4 pc = *(const f32x4*)&gb[PC_OFF + qi * 64 + j4 * 4];
        a += pc[0] * gb[VS_OFF + (j4 * 4 + 0) * 68 + j] +
             pc[1] * gb[VS_OFF + (j4 * 4 + 1) * 68 + j] +
             pc[2] * gb[VS_OFF + (j4 * 4 + 2) * 68 + j] +
             pc[3] * gb[VS_OFF + (j4 * 4 + 3) * 68 + j];
      }
      part[pbase + qi * 64 + j] = a;
    }
    __syncthreads();

    // ---- phase B: local attention, 2x4 half-tiles (register-light) ----
    {
      const int ty = tl >> 4, tx = tl & 15;
      const int c0k = tx * 4;
      const f32x4 skv = *(const f32x4*)&gb[SK_OFF + c0k];
#pragma unroll
      for (int half = 0; half < 2; ++half) {
        const int r0q = ty * 4 + half * 2;   // rows r0q, r0q+1 (ty-private)
        const float sq0 = gb[SQ_OFF + r0q];
        const float sq1 = gb[SQ_OFF + r0q + 1];
        f32x4 X0 = {0.f, 0.f, 0.f, 0.f}, X1 = {0.f, 0.f, 0.f, 0.f};
#pragma unroll
        for (int d4 = 0; d4 < 16; ++d4) {
          f32x4 ww = *(const f32x4*)&gb[WW_OFF + d4 * 4];
          f32x4 q0 = *(const f32x4*)&gb[QS_OFF + r0q * 68 + d4 * 4];
          f32x4 q1 = *(const f32x4*)&gb[QS_OFF + (r0q + 1) * 68 + d4 * 4];
          q0 *= ww; q1 *= ww;
          f32x4 k0 = *(const f32x4*)&gb[KT_OFF + (d4 * 4 + 0) * 68 + c0k];
          f32x4 k1 = *(const f32x4*)&gb[KT_OFF + (d4 * 4 + 1) * 68 + c0k];
          f32x4 k2 = *(const f32x4*)&gb[KT_OFF + (d4 * 4 + 2) * 68 + c0k];
          f32x4 k3 = *(const f32x4*)&gb[KT_OFF + (d4 * 4 + 3) * 68 + c0k];
          X0 += q0[0] * k0 + q0[1] * k1 + q0[2] * k2 + q0[3] * k3;
          X1 += q1[0] * k0 + q1[1] * k1 + q1[2] * k2 + q1[3] * k3;
        }
        X0 = X0 * skv * (sq0 * SCALE);
        X1 = X1 * skv * (sq1 * SCALE);
        float m0 = fmaxf(fmaxf(X0[0], X0[1]), fmaxf(X0[2], X0[3]));
        float m1 = fmaxf(fmaxf(X1[0], X1[1]), fmaxf(X1[2], X1[3]));
#pragma unroll
        for (int o = 1; o < 16; o <<= 1) {
          m0 = fmaxf(m0, __shfl_xor(m0, o));
          m1 = fmaxf(m1, __shfl_xor(m1, o));
        }
        f32x4 P0, P1;
#pragma unroll
        for (int cc = 0; cc < 4; ++cc) {
          P0[cc] = __expf(X0[cc] - m0);
          P1[cc] = __expf(X1[cc] - m1);
        }
        float s0 = P0[0] + P0[1] + P0[2] + P0[3];
        float s1 = P1[0] + P1[1] + P1[2] + P1[3];
#pragma unroll
        for (int o = 1; o < 16; o <<= 1) {
          s0 += __shfl_xor(s0, o);
          s1 += __shfl_xor(s1, o);
        }
        const float li0 = 1.0f / s0, li1 = 1.0f / s1;
        // P overwrites q rows r0q/r0q+1: ty-private rows, same-wave lockstep
        *(f32x4*)&gb[QS_OFF + r0q * 68 + c0k] = P0;
        *(f32x4*)&gb[QS_OFF + (r0q + 1) * 68 + c0k] = P1;
        f32x4 O0 = {0.f, 0.f, 0.f, 0.f}, O1 = {0.f, 0.f, 0.f, 0.f};
#pragma unroll
        for (int j4 = 0; j4 < 16; ++j4) {
          f32x4 p0 = *(const f32x4*)&gb[QS_OFF + r0q * 68 + j4 * 4];
          f32x4 p1 = *(const f32x4*)&gb[QS_OFF + (r0q + 1) * 68 + j4 * 4];
          f32x4 v0 = *(const f32x4*)&gb[VS_OFF + (j4 * 4 + 0) * 68 + c0k];
          f32x4 v1 = *(const f32x4*)&gb[VS_OFF + (j4 * 4 + 1) * 68 + c0k];
          f32x4 v2 = *(const f32x4*)&gb[VS_OFF + (j4 * 4 + 2) * 68 + c0k];
          f32x4 v3 = *(const f32x4*)&gb[VS_OFF + (j4 * 4 + 3) * 68 + c0k];
          O0 += p0[0] * v0 + p0[1] * v1 + p0[2] * v2 + p0[3] * v3;
          O1 += p1[0] * v0 + p1[1] * v1 + p1[2] * v2 + p1[3] * v3;
        }
        O0 *= li0;
        O1 *= li1;
        int orow0 = (widx * 64 + r0q) * 768 + h * 64 + c0k;
        ushort4v h0, l0, h1, l1;
#pragma unroll
        for (int cc = 0; cc < 4; ++cc) {
          float a0 = O0[cc]; ushort hh0 = f2bf(a0);
          h0[cc] = hh0; l0[cc] = f2bf(a0 - bf2f(hh0));
          float a1 = O1[cc]; ushort hh1 = f2bf(a1);
          h1[cc] = hh1; l1[cc] = f2bf(a1 - bf2f(hh1));
        }
        *(ushort4v*)&o_hi[orow0] = h0;
        *(ushort4v*)&o_lo[orow0] = l0;
        *(ushort4v*)&o_hi[orow0 + 768] = h1;
        *(ushort4v*)&o_lo[orow0 + 768] = l1;
      }
    }
    __syncthreads();
  }
}

// ============ P: projection out = o @ w_out + g_term (128x192, 4-plane BK=32) ====
// 256 threads, 80KB LDS -> 2 blocks/CU. grid = 1024, XCD-local decode.
__global__ __launch_bounds__(256, 2) void k_proj8(
    const ushort* __restrict__ o_hi, const ushort* __restrict__ o_lo,
    const ushort* __restrict__ Whi, const ushort* __restrict__ Wlo,
    const float* __restrict__ g_term, float* __restrict__ out) {
  __shared__ __align__(16) char smem[81920];
  const int tid = threadIdx.x;
  const int lane = tid & 63;
  const int wv = tid >> 6;
  const int wm = wv >> 1, wn = wv & 1;
  const int l15 = lane & 15, kq = lane >> 4;
  const int bid = blockIdx.x;
  const int xcd = bid & 7, kk_ = bid >> 3;     // 0..127
  const int cblk = kk_ % 4;
  const int mblk = (kk_ / 4) * 8 + xcd;        // 0..255
  const int r0 = mblk * 128;
  const int cb0 = cblk * 192;

  int gAo[4], lA[4]; bool pA[4];
#pragma unroll
  for (int j = 0; j < 4; ++j) {
    int byo = (j * 256 + tid) * 16;
    pA[j] = byo >= 8192;
    int wb = byo & 8191;
    int row = wb >> 6, sl = (wb >> 4) & 3;
    int kb = sl ^ ((row >> 1) & 3);
    gAo[j] = (r0 + row) * 768 + kb * 8;
    lA[j] = byo;
  }
  int gBo[6], lB[6]; bool pB[6];
#pragma unroll
  for (int j = 0; j < 6; ++j) {
    int byo = (j * 256 + tid) * 16;
    pB[j] = byo >= 12288;
    int wb = pB[j] ? byo - 12288 : byo;
    int row = wb >> 6, sl = (wb >> 4) & 3;
    int kb = sl ^ ((row >> 1) & 3);
    gBo[j] = (cb0 + row) * 768 + kb * 8;
    lB[j] = 16384 + byo;
  }

  f32x4 acc[4][6];
#pragma unroll
  for (int i = 0; i < 4; ++i)
#pragma unroll
    for (int j = 0; j < 6; ++j) acc[i][j] = (f32x4){0.f, 0.f, 0.f, 0.f};

  auto STAGE = [&](int t, int bufi) {
    const int kk = t * 32;
    char* bb = smem + bufi * 40960;
#pragma unroll
    for (int j = 0; j < 4; ++j) {
      const ushort* Ap = pA[j] ? o_lo : o_hi;
      gl_lds16(Ap + gAo[j] + kk, bb + lA[j]);
    }
#pragma unroll
    for (int j = 0; j < 6; ++j) {
      const ushort* Bp = pB[j] ? Wlo : Whi;
      gl_lds16(Bp + gBo[j] + kk, bb + lB[j]);
    }
  };

  auto COMPUTE = [&](int bufi) {
    const char* ba = smem + bufi * 40960;
    short8 ah[4], al[4], bh[6], bl[6];
#pragma unroll
    for (int mf = 0; mf < 4; ++mf) {
      int row = wm * 64 + mf * 16 + l15;
      int so = (kq ^ ((row >> 1) & 3)) << 4;
      ah[mf] = *(const short8*)(ba + row * 64 + so);
      al[mf] = *(const short8*)(ba + 8192 + row * 64 + so);
    }
#pragma unroll
    for (int nf = 0; nf < 6; ++nf) {
      int row = wn * 96 + nf * 16 + l15;
      int so = (kq ^ ((row >> 1) & 3)) << 4;
      bh[nf] = *(const short8*)(ba + 16384 + row * 64 + so);
      bl[nf] = *(const short8*)(ba + 28672 + row * 64 + so);
    }
    __builtin_amdgcn_s_setprio(1);
#pragma unroll
    for (int mf = 0; mf < 4; ++mf)
#pragma unroll
      for (int nf = 0; nf < 6; ++nf) {
        acc[mf][nf] = __builtin_amdgcn_mfma_f32_16x16x32_bf16(ah[mf], bh[nf], acc[mf][nf], 0, 0, 0);
        acc[mf][nf] = __builtin_amdgcn_mfma_f32_16x16x32_bf16(ah[mf], bl[nf], acc[mf][nf], 0, 0, 0);
        acc[mf][nf] = __builtin_amdgcn_mfma_f32_16x16x32_bf16(al[mf], bh[nf], acc[mf][nf], 0, 0, 0);
      }
    __builtin_amdgcn_s_setprio(0);
  };

  STAGE(0, 0); STAGE(1, 1);
  WAITV(10); BAR();
  for (int t = 0; t < 24; ++t) {
    int cur = t & 1;
    COMPUTE(cur);
    BAR();
    if (t < 22) { STAGE(t + 2, cur); WAITV(10); }
    else { WAITV(0); }
    BAR();
  }

#pragma unroll
  for (int mf = 0; mf < 4; ++mf) {
    int prow0 = r0 + wm * 64 + mf * 16 + kq * 4;
#pragma unroll
    for (int nf = 0; nf < 6; ++nf) {
      int col = cb0 + wn * 96 + nf * 16 + l15;
#pragma unroll
      for (int e = 0; e < 4; ++e) {
        int p = prow0 + e;
        out[nat_row(p) * 768 + col] = acc[mf][nf][e] + g_term[(p >> 12) * 768 + col];
      }
    }
  }
}

// ============ G3: combine global-attn partials -> og_mean (B x 768) ============
__global__ void k_greduce(const float* __restrict__ qkv_g,
                          const float* __restrict__ part,
                          float* __restrict__ og_mean) {
  __shared__ float red[4][64];
  int bh = blockIdx.x;
  int b = bh / 12, h = bh - b * 12;
  int tid = threadIdx.x;
  int qi = tid >> 6, d = tid & 63;
  float M = -1e30f, L = 0.f, A = 0.f;
  float qd = qkv_g[qi * 2304 + h * 64 + d];
#pragma unroll
  for (int gk = 0; gk < 4; ++gk) {
    float kd = qkv_g[gk * 2304 + 768 + h * 64 + d];
    float prod = qd * kd;
#pragma unroll
    for (int o = 1; o < 64; o <<= 1) prod += __shfl_xor(prod, o);
    float s = prod * SCALE;
    float Mn = fmaxf(M, s);
    float f = __expf(M - Mn), e = __expf(s - Mn);
    float vd = qkv_g[gk * 2304 + 1536 + h * 64 + d];
    A = A * f + e * vd;
    L = L * f + e;
    M = Mn;
  }
  for (int p = 0; p < 64; ++p) {
    int pbase = ((b * 12 + h) * 64 + p) * 272;
    float mp = part[pbase + 256 + qi];
    float lp = part[pbase + 260 + qi];
    float ap = part[pbase + qi * 64 + d];
    float Mn = fmaxf(M, mp);
    float f = __expf(M - Mn), e = __expf(mp - Mn);
    A = A * f + ap * e;
    L = L * f + lp * e;
    M = Mn;
  }
  red[qi][d] = A / L;
  __syncthreads();
  if (tid < 64) {
    float s = (red[0][d] + red[1][d] + red[2][d] + red[3][d]) * 0.25f;
    og_mean[b * 768 + h * 64 + d] = s;
  }
}

// ============ G4: g_term = og_mean @ w_out (B x 768), fp32 ============
__global__ void k_gterm(const float* __restrict__ og_mean,
                        const float* __restrict__ w_out,
                        float* __restrict__ g_term) {
  int idx = blockIdx.x * 256 + threadIdx.x;   // 0..6143
  int b = idx / 768, c = idx - b * 768;
  const float* op = og_mean + b * 768;
  float s = 0.f;
  for (int d = 0; d < 768; ++d) s += op[d] * w_out[d * 768 + c];
  g_term[idx] = s;
}

extern "C" void kernel_launch(void* const* d_in, const int* in_sizes, int n_in,
                              void* d_out, int out_size, void* d_ws, size_t ws_size,
                              hipStream_t stream) {
  const float* x      = (const float*)d_in[0];
  const float* w_qkv  = (const float*)d_in[1];
  const float* w_out  = (const float*)d_in[2];
  const float* qnw    = (const float*)d_in[3];
  const float* knw    = (const float*)d_in[4];
  const float* gtok   = (const float*)d_in[5];
  float* out = (float*)d_out;

  // ---- ws layout (~117 MB) ----
  ushort* WhiQ = (ushort*)d_ws;                 // 2304*768
  ushort* WloQ = WhiQ + 2304 * 768;
  ushort* WhiO = WloQ + 2304 * 768;             // 768*768
  ushort* WloO = WhiO + 768 * 768;
  ushort* o_hi = WloO + 768 * 768;              // 32768*768
  ushort* o_lo = o_hi + 32768 * 768;
  float* qkv_g   = (float*)(o_lo + 32768 * 768);
  float* part    = qkv_g + 9216;                // 8*12*64*272
  float* og_mean = part + 8 * 12 * 64 * 272;
  float* g_term  = og_mean + 6144;

  // x hi/lo planes live in d_out until the final projection overwrites it
  ushort* xh = (ushort*)d_out;                  // 32768*768
  ushort* xl = xh + 32768 * 768;

  k_prep  <<<dim3(36, 12), 256, 0, stream>>>(w_qkv, 2304, 0, WhiQ, WloQ);
  k_prep  <<<dim3(12, 12), 256, 0, stream>>>(w_out,  768, 1, WhiO, WloO);
  k_gqkv  <<<36,    256, 0, stream>>>(gtok, w_qkv, qkv_g);
  k_xsplit<<<12288, 256, 0, stream>>>(x, xh, xl);

  k_fused <<<3072, 256, 0, stream>>>(xh, xl, WhiQ, WloQ, qnw, knw, qkv_g, part, o_hi, o_lo);

  k_greduce<<<96, 256, 0, stream>>>(qkv_g, part, og_mean);
  k_gterm  <<<24, 256, 0, stream>>>(og_mean, w_out, g_term);
  k_proj8 <<<1024, 256, 0, stream>>>(o_hi, o_lo, WhiO, WloO, g_term, out);
}